// Round 1
// baseline (252.331 us; speedup 1.0000x reference)
//
#include <hip/hip_runtime.h>
#include <hip/hip_bf16.h>
#include <math.h>

#define B_   8
#define C_   512
#define H_   96
#define W_   96
#define HW   9216
#define K_   64
#define PH   12
#define PW   12
#define NT   96     // n-tile per block in main kernel
#define CCH  32     // c-chunk
#define NBLK 96     // n-blocks per batch = HW/NT

// ws layout (bytes)
#define OFF_PARTIAL 0u                    // float[8][73728]  (chunk-major)
#define OFF_DESC    2359296u              // float[B*C*K] layout [b][c][k]
#define OFF_ROWA    3407872u              // int[512]
#define OFF_COLA    3409920u              // int[512]
#define OFF_FLATA   3411968u              // int[512]
#define OFF_CANDV   3414016u              // float[512*96]
#define OFF_CANDN   3610624u              // int[512*96]
#define OFF_OFFR    3807232u              // int[512]
#define OFF_OFFC    3809280u              // int[512]

// ---------------- kernel 1: partial channel sums ----------------
// grid (288, 8 chunks), block 256. part[chunk][b*HW+hw] = sum of 64 channels.
__global__ __launch_bounds__(256) void k_partial(const float* __restrict__ A,
                                                 float* __restrict__ part) {
    int idx = blockIdx.x * 256 + threadIdx.x;      // b*HW + hw
    int chunk = blockIdx.y;
    int b = idx / HW, hw = idx - b * HW;
    const float* p = A + ((size_t)(b * C_ + chunk * 64)) * HW + hw;
    float s = 0.f;
#pragma unroll
    for (int i = 0; i < 64; ++i) s += p[(size_t)i * HW];
    part[chunk * (B_ * HW) + idx] = s;
}

// ---------------- kernel 2: per-region argmax (first max) ----------------
// grid (64 regions, 8 batches), block 64 (one wave).
__global__ void k_select(const float* __restrict__ part, int* __restrict__ rowA,
                         int* __restrict__ colA, int* __restrict__ flatA) {
    int k = blockIdx.x, b = blockIdx.y, lane = threadIdx.x;
    int gi = k >> 3, gj = k & 7;
    float bv = -1e30f; int bp = 1 << 20;
    for (int p = lane; p < PH * PW; p += 64) {   // p ascending per lane
        int lr = p / PW, lc = p - lr * PW;
        int hw = (gi * PH + lr) * W_ + gj * PW + lc;
        float v = 0.f;
#pragma unroll
        for (int ch = 0; ch < 8; ++ch) v += part[ch * (B_ * HW) + b * HW + hw];
        if (v > bv || (v == bv && p < bp)) { bv = v; bp = p; }
    }
    for (int m = 1; m < 64; m <<= 1) {
        float ov = __shfl_xor(bv, m);
        int   op = __shfl_xor(bp, m);
        if (ov > bv || (ov == bv && op < bp)) { bv = ov; bp = op; }
    }
    if (lane == 0) {
        int lr = bp / PW, lc = bp - lr * PW;
        int r = gi * PH + lr, c = gj * PW + lc;
        rowA[b * K_ + k] = r; colA[b * K_ + k] = c; flatA[b * K_ + k] = r * W_ + c;
    }
}

// ---------------- kernel 3: gather descriptors desc[b][c][k] ----------------
__global__ __launch_bounds__(256) void k_gather(const float* __restrict__ A,
                                                const int* __restrict__ flatA,
                                                float* __restrict__ desc) {
    int idx = blockIdx.x * 256 + threadIdx.x;   // b(3b)|c(9b)|k(6b)
    int k = idx & 63, c = (idx >> 6) & 511, b = idx >> 15;
    desc[idx] = A[((size_t)(b * C_ + c)) * HW + flatA[(b << 6) + k]];
}

// ---------------- kernel 4: cross GEMM + fused argmin ----------------
// grid (NBLK=96, 8), block 256. Thread tile: 8 k x 3 n.
__global__ __launch_bounds__(256) void k_main(const float* __restrict__ FB,
                                              const float* __restrict__ desc,
                                              float* __restrict__ candV,
                                              int* __restrict__ candN) {
    __shared__ float fbs[CCH][NT];     // 12 KB
    __shared__ float dss[CCH][K_];     // 8 KB
    __shared__ float fbsq_s[NT];
    int b = blockIdx.y, nb = blockIdx.x * NT;
    int tid = threadIdx.x;
    int kg = tid >> 5;        // 0..7 -> k = kg*8 + kk
    int ng = tid & 31;        // n = ng*3 + nn
    float acc[8][3];
#pragma unroll
    for (int i = 0; i < 8; ++i)
#pragma unroll
        for (int j = 0; j < 3; ++j) acc[i][j] = 0.f;
    float fbsq_acc = 0.f;
    const size_t baseB = (size_t)b * C_ * HW + nb;
    const float* descb = desc + (size_t)b * C_ * K_;

    for (int c0 = 0; c0 < C_; c0 += CCH) {
        __syncthreads();
        // stage fb chunk: 32c x 96n = 3072 elems, 12/thread, coalesced in n
#pragma unroll
        for (int i = 0; i < (CCH * NT) / 256; ++i) {
            int e = tid + i * 256;
            int c = e / NT, n = e - c * NT;
            fbs[c][n] = FB[baseB + (size_t)(c0 + c) * HW + n];
        }
        // stage desc chunk: 32c x 64k = 2048 elems, 8/thread, coalesced
#pragma unroll
        for (int i = 0; i < (CCH * K_) / 256; ++i) {
            int e = tid + i * 256;
            int c = e >> 6, k = e & 63;
            dss[c][k] = descb[(c0 + c) * K_ + k];
        }
        __syncthreads();
        // deterministic fbsq accumulation: thread t (<96) owns column n=t
        if (tid < NT) {
#pragma unroll
            for (int c = 0; c < CCH; ++c) { float v = fbs[c][tid]; fbsq_acc = fmaf(v, v, fbsq_acc); }
        }
        // main FMA: per c, 2x b128 broadcast (desc) + 3x b32 stride-3 (fb), 24 FMA
#pragma unroll 8
        for (int c = 0; c < CCH; ++c) {
            const float4 d0 = *(const float4*)&dss[c][kg * 8];
            const float4 d1 = *(const float4*)&dss[c][kg * 8 + 4];
            float dk[8] = {d0.x, d0.y, d0.z, d0.w, d1.x, d1.y, d1.z, d1.w};
            float fn[3] = {fbs[c][ng * 3], fbs[c][ng * 3 + 1], fbs[c][ng * 3 + 2]};
#pragma unroll
            for (int kk = 0; kk < 8; ++kk)
#pragma unroll
                for (int nn = 0; nn < 3; ++nn)
                    acc[kk][nn] = fmaf(dk[kk], fn[nn], acc[kk][nn]);
        }
    }
    if (tid < NT) fbsq_s[tid] = fbsq_acc;
    __syncthreads();
    float fsq[3] = {fbsq_s[ng * 3], fbsq_s[ng * 3 + 1], fbsq_s[ng * 3 + 2]};
#pragma unroll
    for (int kk = 0; kk < 8; ++kk) {
        float bv = 1e30f; int bn = 1 << 28;
#pragma unroll
        for (int nn = 0; nn < 3; ++nn) {          // ascending n -> first-min
            float sc = fsq[nn] - 2.f * acc[kk][nn];
            int n = ng * 3 + nn;
            if (sc < bv) { bv = sc; bn = n; }
        }
        for (int m = 1; m < 32; m <<= 1) {        // reduce across the 32 n-groups
            float ov = __shfl_xor(bv, m);
            int   on = __shfl_xor(bn, m);
            if (ov < bv || (ov == bv && on < bn)) { bv = ov; bn = on; }
        }
        if (ng == 0) {
            int k = kg * 8 + kk;
            candV[(b * K_ + k) * NBLK + blockIdx.x] = bv;
            candN[(b * K_ + k) * NBLK + blockIdx.x] = nb + bn;
        }
    }
}

// ---------------- kernel 5: cross-block argmin + offsets ----------------
// grid (64, 8), block 64.
__global__ void k_reduce(const float* __restrict__ candV, const int* __restrict__ candN,
                         const int* __restrict__ rowA, const int* __restrict__ colA,
                         int* __restrict__ offR, int* __restrict__ offC) {
    int k = blockIdx.x, b = blockIdx.y, lane = threadIdx.x;
    int base = (b * K_ + k) * NBLK;
    float bv = candV[base + lane]; int bn = candN[base + lane];
    if (lane < NBLK - 64) {
        float ov = candV[base + 64 + lane]; int on = candN[base + 64 + lane];
        if (ov < bv || (ov == bv && on < bn)) { bv = ov; bn = on; }
    }
    for (int m = 1; m < 64; m <<= 1) {
        float ov = __shfl_xor(bv, m);
        int   on = __shfl_xor(bn, m);
        if (ov < bv || (ov == bv && on < bn)) { bv = ov; bn = on; }
    }
    if (lane == 0) {
        int rB = bn / W_, cB = bn - rB * W_;
        offR[b * K_ + k] = rowA[b * K_ + k] - rB;   // -(rowB - rowA)
        offC[b * K_ + k] = colA[b * K_ + k] - cB;
    }
}

// ---------------- kernel 6: per-batch mode (first-index tie-break) ----------------
__global__ void k_mode(const int* __restrict__ offR, const int* __restrict__ offC,
                       int* __restrict__ out) {
    __shared__ int r_s[64], c_s[64];
    int b = blockIdx.x, k = threadIdx.x;
    r_s[k] = offR[b * 64 + k]; c_s[k] = offC[b * 64 + k];
    __syncthreads();
    int mr = r_s[k], mc = c_s[k], cnt = 0;
#pragma unroll
    for (int j = 0; j < 64; ++j) cnt += (r_s[j] == mr && c_s[j] == mc) ? 1 : 0;
    int bk = k, bc = cnt;
    for (int m = 1; m < 64; m <<= 1) {
        int oc = __shfl_xor(bc, m);
        int ok = __shfl_xor(bk, m);
        if (oc > bc || (oc == bc && ok < bk)) { bc = oc; bk = ok; }
    }
    if (k == 0) { out[b * 2] = r_s[bk]; out[b * 2 + 1] = c_s[bk]; }
}

extern "C" void kernel_launch(void* const* d_in, const int* in_sizes, int n_in,
                              void* d_out, int out_size, void* d_ws, size_t ws_size,
                              hipStream_t stream) {
    const float* A  = (const float*)d_in[0];
    const float* FB = (const float*)d_in[1];
    char* ws = (char*)d_ws;
    float* part  = (float*)(ws + OFF_PARTIAL);
    float* desc  = (float*)(ws + OFF_DESC);
    int*   rowA  = (int*)(ws + OFF_ROWA);
    int*   colA  = (int*)(ws + OFF_COLA);
    int*   flatA = (int*)(ws + OFF_FLATA);
    float* candV = (float*)(ws + OFF_CANDV);
    int*   candN = (int*)(ws + OFF_CANDN);
    int*   offR  = (int*)(ws + OFF_OFFR);
    int*   offC  = (int*)(ws + OFF_OFFC);
    int*   out   = (int*)d_out;

    k_partial<<<dim3((B_ * HW) / 256, 8), 256, 0, stream>>>(A, part);
    k_select<<<dim3(K_, B_), 64, 0, stream>>>(part, rowA, colA, flatA);
    k_gather<<<dim3((B_ * C_ * K_) / 256), 256, 0, stream>>>(A, flatA, desc);
    k_main<<<dim3(NBLK, B_), 256, 0, stream>>>(FB, desc, candV, candN);
    k_reduce<<<dim3(K_, B_), 64, 0, stream>>>(candV, candN, rowA, colA, offR, offC);
    k_mode<<<dim3(B_), 64, 0, stream>>>(offR, offC, out);
}

// Round 2
// 211.156 us; speedup vs baseline: 1.1950x; 1.1950x over previous
//
#include <hip/hip_runtime.h>
#include <hip/hip_bf16.h>
#include <math.h>

#define B_   8
#define C_   512
#define H_   96
#define W_   96
#define HW   9216
#define K_   64
#define PH   12
#define PW   12
#define NT   128    // n-tile per block in main kernel
#define CCH  32     // c-chunk
#define NBLK 72     // n-blocks per batch = HW/NT

// ws layout (bytes)
#define OFF_PARTIAL 0u                    // float[8][73728]  (chunk-major)
#define OFF_DESC    2359296u              // float[B*C*K] layout [b][c][k]
#define OFF_ROWA    3407872u              // int[512]
#define OFF_COLA    3409920u              // int[512]
#define OFF_FLATA   3411968u              // int[512]
#define OFF_CANDV   3414016u              // float[512*NBLK] (<=96 reserved)
#define OFF_CANDN   3610624u              // int[512*NBLK]
#define OFF_OFFR    3807232u              // int[512]
#define OFF_OFFC    3809280u              // int[512]

// ---------------- kernel 1: partial channel sums ----------------
__global__ __launch_bounds__(256) void k_partial(const float* __restrict__ A,
                                                 float* __restrict__ part) {
    int idx = blockIdx.x * 256 + threadIdx.x;      // b*HW + hw
    int chunk = blockIdx.y;
    int b = idx / HW, hw = idx - b * HW;
    const float* p = A + ((size_t)(b * C_ + chunk * 64)) * HW + hw;
    float s = 0.f;
#pragma unroll
    for (int i = 0; i < 64; ++i) s += p[(size_t)i * HW];
    part[chunk * (B_ * HW) + idx] = s;
}

// ---------------- kernel 2: per-region argmax (first max) ----------------
__global__ void k_select(const float* __restrict__ part, int* __restrict__ rowA,
                         int* __restrict__ colA, int* __restrict__ flatA) {
    int k = blockIdx.x, b = blockIdx.y, lane = threadIdx.x;
    int gi = k >> 3, gj = k & 7;
    float bv = -1e30f; int bp = 1 << 20;
    for (int p = lane; p < PH * PW; p += 64) {
        int lr = p / PW, lc = p - lr * PW;
        int hw = (gi * PH + lr) * W_ + gj * PW + lc;
        float v = 0.f;
#pragma unroll
        for (int ch = 0; ch < 8; ++ch) v += part[ch * (B_ * HW) + b * HW + hw];
        if (v > bv || (v == bv && p < bp)) { bv = v; bp = p; }
    }
    for (int m = 1; m < 64; m <<= 1) {
        float ov = __shfl_xor(bv, m);
        int   op = __shfl_xor(bp, m);
        if (ov > bv || (ov == bv && op < bp)) { bv = ov; bp = op; }
    }
    if (lane == 0) {
        int lr = bp / PW, lc = bp - lr * PW;
        int r = gi * PH + lr, c = gj * PW + lc;
        rowA[b * K_ + k] = r; colA[b * K_ + k] = c; flatA[b * K_ + k] = r * W_ + c;
    }
}

// ---------------- kernel 3: gather descriptors desc[b][c][k] ----------------
__global__ __launch_bounds__(256) void k_gather(const float* __restrict__ A,
                                                const int* __restrict__ flatA,
                                                float* __restrict__ desc) {
    int idx = blockIdx.x * 256 + threadIdx.x;   // b(3b)|c(9b)|k(6b)
    int k = idx & 63, c = (idx >> 6) & 511, b = idx >> 15;
    desc[idx] = A[((size_t)(b * C_ + c)) * HW + flatA[(b << 6) + k]];
}

// ---------------- kernel 4: cross GEMM + fused argmin ----------------
// grid (NBLK=72, 8), block 128 (2 waves). Thread tile: 8 k x 8 n.
// Thread (kg=tid>>4, ng=tid&15): k = kg*8+kk, n = nb + {ng*4+j, 64+ng*4+j}.
__global__ __launch_bounds__(128) void k_main(const float* __restrict__ FB,
                                              const float* __restrict__ desc,
                                              float* __restrict__ candV,
                                              int* __restrict__ candN) {
    __shared__ float fbs[CCH][NT];      // 16 KB
    __shared__ float dss[CCH][K_];      // 8 KB
    __shared__ float4 pf[128];          // 2 KB
    __shared__ float fbsq_s[NT];
    int b = blockIdx.y, nb = blockIdx.x * NT;
    int tid = threadIdx.x;
    int kg = tid >> 4, ng = tid & 15;
    float acc[8][8];
#pragma unroll
    for (int i = 0; i < 8; ++i)
#pragma unroll
        for (int j = 0; j < 8; ++j) acc[i][j] = 0.f;
    float4 sq4 = make_float4(0.f, 0.f, 0.f, 0.f);
    const size_t baseB = (size_t)b * C_ * HW + nb;
    const float* descb = desc + (size_t)b * C_ * K_;

    for (int c0 = 0; c0 < C_; c0 += CCH) {
        __syncthreads();
        // stage fb chunk: 32c x 128n, float4 per thread x8; fuse fbsq partial
#pragma unroll
        for (int i = 0; i < 8; ++i) {
            int e = i * 512 + tid * 4;
            int c = e >> 7, n = e & 127;
            float4 v = *(const float4*)&FB[baseB + (size_t)(c0 + c) * HW + n];
            *(float4*)&fbs[c][n] = v;
            sq4.x = fmaf(v.x, v.x, sq4.x);
            sq4.y = fmaf(v.y, v.y, sq4.y);
            sq4.z = fmaf(v.z, v.z, sq4.z);
            sq4.w = fmaf(v.w, v.w, sq4.w);
        }
        // stage desc chunk: 32c x 64k, float4 per thread x4
#pragma unroll
        for (int i = 0; i < 4; ++i) {
            int e = i * 512 + tid * 4;
            int c = e >> 6, k = e & 63;
            *(float4*)&dss[c][k] = *(const float4*)&descb[(size_t)(c0 + c) * K_ + k];
        }
        __syncthreads();
#pragma unroll 8
        for (int c = 0; c < CCH; ++c) {
            const float4 d0 = *(const float4*)&dss[c][kg * 8];
            const float4 d1 = *(const float4*)&dss[c][kg * 8 + 4];
            const float4 f0 = *(const float4*)&fbs[c][ng * 4];
            const float4 f1 = *(const float4*)&fbs[c][64 + ng * 4];
            float dk[8] = {d0.x, d0.y, d0.z, d0.w, d1.x, d1.y, d1.z, d1.w};
            float fn[8] = {f0.x, f0.y, f0.z, f0.w, f1.x, f1.y, f1.z, f1.w};
#pragma unroll
            for (int kk = 0; kk < 8; ++kk)
#pragma unroll
                for (int j = 0; j < 8; ++j)
                    acc[kk][j] = fmaf(dk[kk], fn[j], acc[kk][j]);
        }
    }
    // reduce fbsq partials: thread's quad is (tid&31)*4; 4 threads share a quad
    pf[tid] = sq4;
    __syncthreads();
    if (tid < 32) {
        float4 a = pf[tid], b2 = pf[tid + 32], c2 = pf[tid + 64], d2 = pf[tid + 96];
        float4 s = make_float4(a.x + b2.x + c2.x + d2.x, a.y + b2.y + c2.y + d2.y,
                               a.z + b2.z + c2.z + d2.z, a.w + b2.w + c2.w + d2.w);
        *(float4*)&fbsq_s[tid * 4] = s;
    }
    __syncthreads();
    const float4 q0 = *(const float4*)&fbsq_s[ng * 4];
    const float4 q1 = *(const float4*)&fbsq_s[64 + ng * 4];
    float fsq[8] = {q0.x, q0.y, q0.z, q0.w, q1.x, q1.y, q1.z, q1.w};
#pragma unroll
    for (int kk = 0; kk < 8; ++kk) {
        float bv = 1e30f; int bn = 1 << 28;
#pragma unroll
        for (int j = 0; j < 8; ++j) {          // n ascending within thread
            float sc = fsq[j] - 2.f * acc[kk][j];
            int n = (j < 4) ? (ng * 4 + j) : (64 + ng * 4 + (j - 4));
            if (sc < bv) { bv = sc; bn = n; }
        }
        for (int m = 1; m < 16; m <<= 1) {     // reduce across 16 ng lanes
            float ov = __shfl_xor(bv, m);
            int   on = __shfl_xor(bn, m);
            if (ov < bv || (ov == bv && on < bn)) { bv = ov; bn = on; }
        }
        if (ng == 0) {
            int k = kg * 8 + kk;
            candV[(b * K_ + k) * NBLK + blockIdx.x] = bv;
            candN[(b * K_ + k) * NBLK + blockIdx.x] = nb + bn;
        }
    }
}

// ---------------- kernel 5: cross-block argmin + offsets ----------------
// grid (64, 8), block 64. NBLK=72 candidates per (b,k).
__global__ void k_reduce(const float* __restrict__ candV, const int* __restrict__ candN,
                         const int* __restrict__ rowA, const int* __restrict__ colA,
                         int* __restrict__ offR, int* __restrict__ offC) {
    int k = blockIdx.x, b = blockIdx.y, lane = threadIdx.x;
    int base = (b * K_ + k) * NBLK;
    float bv = candV[base + lane]; int bn = candN[base + lane];
    if (lane < NBLK - 64) {
        float ov = candV[base + 64 + lane]; int on = candN[base + 64 + lane];
        if (ov < bv || (ov == bv && on < bn)) { bv = ov; bn = on; }
    }
    for (int m = 1; m < 64; m <<= 1) {
        float ov = __shfl_xor(bv, m);
        int   on = __shfl_xor(bn, m);
        if (ov < bv || (ov == bv && on < bn)) { bv = ov; bn = on; }
    }
    if (lane == 0) {
        int rB = bn / W_, cB = bn - rB * W_;
        offR[b * K_ + k] = rowA[b * K_ + k] - rB;   // -(rowB - rowA)
        offC[b * K_ + k] = colA[b * K_ + k] - cB;
    }
}

// ---------------- kernel 6: per-batch mode (first-index tie-break) ----------------
__global__ void k_mode(const int* __restrict__ offR, const int* __restrict__ offC,
                       int* __restrict__ out) {
    __shared__ int r_s[64], c_s[64];
    int b = blockIdx.x, k = threadIdx.x;
    r_s[k] = offR[b * 64 + k]; c_s[k] = offC[b * 64 + k];
    __syncthreads();
    int mr = r_s[k], mc = c_s[k], cnt = 0;
#pragma unroll
    for (int j = 0; j < 64; ++j) cnt += (r_s[j] == mr && c_s[j] == mc) ? 1 : 0;
    int bk = k, bc = cnt;
    for (int m = 1; m < 64; m <<= 1) {
        int oc = __shfl_xor(bc, m);
        int ok = __shfl_xor(bk, m);
        if (oc > bc || (oc == bc && ok < bk)) { bc = oc; bk = ok; }
    }
    if (k == 0) { out[b * 2] = r_s[bk]; out[b * 2 + 1] = c_s[bk]; }
}

extern "C" void kernel_launch(void* const* d_in, const int* in_sizes, int n_in,
                              void* d_out, int out_size, void* d_ws, size_t ws_size,
                              hipStream_t stream) {
    const float* A  = (const float*)d_in[0];
    const float* FB = (const float*)d_in[1];
    char* ws = (char*)d_ws;
    float* part  = (float*)(ws + OFF_PARTIAL);
    float* desc  = (float*)(ws + OFF_DESC);
    int*   rowA  = (int*)(ws + OFF_ROWA);
    int*   colA  = (int*)(ws + OFF_COLA);
    int*   flatA = (int*)(ws + OFF_FLATA);
    float* candV = (float*)(ws + OFF_CANDV);
    int*   candN = (int*)(ws + OFF_CANDN);
    int*   offR  = (int*)(ws + OFF_OFFR);
    int*   offC  = (int*)(ws + OFF_OFFC);
    int*   out   = (int*)d_out;

    k_partial<<<dim3((B_ * HW) / 256, 8), 256, 0, stream>>>(A, part);
    k_select<<<dim3(K_, B_), 64, 0, stream>>>(part, rowA, colA, flatA);
    k_gather<<<dim3((B_ * C_ * K_) / 256), 256, 0, stream>>>(A, flatA, desc);
    k_main<<<dim3(NBLK, B_), 128, 0, stream>>>(FB, desc, candV, candN);
    k_reduce<<<dim3(K_, B_), 64, 0, stream>>>(candV, candN, rowA, colA, offR, offC);
    k_mode<<<dim3(B_), 64, 0, stream>>>(offR, offC, out);
}

// Round 3
// 130.722 us; speedup vs baseline: 1.9303x; 1.6153x over previous
//
#include <hip/hip_runtime.h>
#include <hip/hip_bf16.h>
#include <math.h>

#define B_   8
#define C_   512
#define H_   96
#define W_   96
#define HW   9216
#define K_   64
#define PH   12
#define PW   12
#define NT   64     // n-tile per block in main kernel
#define CCH  32     // c-chunk
#define NBLK 144    // n-blocks per batch = HW/NT

// ws layout (bytes). candV/candN alias the dead `part` region (k_select is done
// before k_main writes them; k_gather only reads A+flatA).
#define OFF_PARTIAL 0u                    // float[8][73728]  (chunk-major) -- dead after k_select
#define OFF_CANDV   0u                    // float[512*NBLK]
#define OFF_CANDN   294912u               // int[512*NBLK]
#define OFF_DESC    2359296u              // float[B*C*K] layout [b][c][k]
#define OFF_ROWA    3407872u              // int[512]
#define OFF_COLA    3409920u              // int[512]
#define OFF_FLATA   3411968u              // int[512]
#define OFF_OFFR    3414016u              // int[512]
#define OFF_OFFC    3416064u              // int[512]

// ---------------- kernel 1: partial channel sums (float4) ----------------
// grid (72, 8 chunks), block 256. part[chunk][b*HW+hw] = sum of 64 channels.
__global__ __launch_bounds__(256) void k_partial(const float* __restrict__ A,
                                                 float* __restrict__ part) {
    int idx4 = blockIdx.x * 256 + threadIdx.x;     // float4 index over b*HW/4
    int chunk = blockIdx.y;
    int b = idx4 / (HW / 4), hw4 = idx4 - b * (HW / 4);
    const float* p = A + ((size_t)(b * C_ + chunk * 64)) * HW + hw4 * 4;
    float4 s = make_float4(0.f, 0.f, 0.f, 0.f);
#pragma unroll
    for (int i = 0; i < 64; ++i) {
        float4 v = *(const float4*)&p[(size_t)i * HW];
        s.x += v.x; s.y += v.y; s.z += v.z; s.w += v.w;
    }
    *(float4*)&part[chunk * (B_ * HW) + b * HW + hw4 * 4] = s;
}

// ---------------- kernel 2: per-region argmax (first max) ----------------
__global__ void k_select(const float* __restrict__ part, int* __restrict__ rowA,
                         int* __restrict__ colA, int* __restrict__ flatA) {
    int k = blockIdx.x, b = blockIdx.y, lane = threadIdx.x;
    int gi = k >> 3, gj = k & 7;
    float bv = -1e30f; int bp = 1 << 20;
    for (int p = lane; p < PH * PW; p += 64) {
        int lr = p / PW, lc = p - lr * PW;
        int hw = (gi * PH + lr) * W_ + gj * PW + lc;
        float v = 0.f;
#pragma unroll
        for (int ch = 0; ch < 8; ++ch) v += part[ch * (B_ * HW) + b * HW + hw];
        if (v > bv || (v == bv && p < bp)) { bv = v; bp = p; }
    }
    for (int m = 1; m < 64; m <<= 1) {
        float ov = __shfl_xor(bv, m);
        int   op = __shfl_xor(bp, m);
        if (ov > bv || (ov == bv && op < bp)) { bv = ov; bp = op; }
    }
    if (lane == 0) {
        int lr = bp / PW, lc = bp - lr * PW;
        int r = gi * PH + lr, c = gj * PW + lc;
        rowA[b * K_ + k] = r; colA[b * K_ + k] = c; flatA[b * K_ + k] = r * W_ + c;
    }
}

// ---------------- kernel 3: gather descriptors desc[b][c][k] ----------------
__global__ __launch_bounds__(256) void k_gather(const float* __restrict__ A,
                                                const int* __restrict__ flatA,
                                                float* __restrict__ desc) {
    int idx = blockIdx.x * 256 + threadIdx.x;   // b(3b)|c(9b)|k(6b)
    int k = idx & 63, c = (idx >> 6) & 511, b = idx >> 15;
    desc[idx] = A[((size_t)(b * C_ + c)) * HW + flatA[(b << 6) + k]];
}

// ---------------- kernel 4: cross GEMM + fused argmin ----------------
// grid (NBLK=144, 2 k-splits, 8 batches), block 128 (2 waves).
// Thread tile: 4 k x 4 n. kg=tid>>4 (0..7): k = ks*32 + kg*4 + kk.
// ng=tid&15: n = nb + ng*4 + j.
__global__ __launch_bounds__(128) void k_main(const float* __restrict__ FB,
                                              const float* __restrict__ desc,
                                              float* __restrict__ candV,
                                              int* __restrict__ candN) {
    __shared__ float fbs[CCH][NT];      // 8 KB
    __shared__ float dsk[CCH][32];      // 4 KB
    __shared__ float4 pf[128];          // 2 KB
    __shared__ float fbsq_s[NT];
    int b = blockIdx.z, ks = blockIdx.y, nb = blockIdx.x * NT;
    int tid = threadIdx.x;
    int kg = tid >> 4, ng = tid & 15;
    float acc[4][4];
#pragma unroll
    for (int i = 0; i < 4; ++i)
#pragma unroll
        for (int j = 0; j < 4; ++j) acc[i][j] = 0.f;
    float4 sq4 = make_float4(0.f, 0.f, 0.f, 0.f);
    const size_t baseB = (size_t)b * C_ * HW + nb;
    const float* descb = desc + (size_t)b * C_ * K_ + ks * 32;

    for (int c0 = 0; c0 < C_; c0 += CCH) {
        __syncthreads();
        // stage fb chunk: 32c x 64n = 2048, float4 x4/thread; fused fbsq partial
#pragma unroll
        for (int i = 0; i < 4; ++i) {
            int e = i * 512 + tid * 4;
            int c = e >> 6, n = e & 63;
            float4 v = *(const float4*)&FB[baseB + (size_t)(c0 + c) * HW + n];
            *(float4*)&fbs[c][n] = v;
            sq4.x = fmaf(v.x, v.x, sq4.x);
            sq4.y = fmaf(v.y, v.y, sq4.y);
            sq4.z = fmaf(v.z, v.z, sq4.z);
            sq4.w = fmaf(v.w, v.w, sq4.w);
        }
        // stage desc k-slice: 32c x 32k = 1024, float4 x2/thread
#pragma unroll
        for (int i = 0; i < 2; ++i) {
            int e = i * 512 + tid * 4;
            int c = e >> 5, k2 = e & 31;
            *(float4*)&dsk[c][k2] = *(const float4*)&descb[(size_t)(c0 + c) * K_ + k2];
        }
        __syncthreads();
#pragma unroll 8
        for (int c = 0; c < CCH; ++c) {
            const float4 d0 = *(const float4*)&dsk[c][kg * 4];
            const float4 f0 = *(const float4*)&fbs[c][ng * 4];
            float dk[4] = {d0.x, d0.y, d0.z, d0.w};
            float fn[4] = {f0.x, f0.y, f0.z, f0.w};
#pragma unroll
            for (int kk = 0; kk < 4; ++kk)
#pragma unroll
                for (int j = 0; j < 4; ++j)
                    acc[kk][j] = fmaf(dk[kk], fn[j], acc[kk][j]);
        }
    }
    // fbsq: thread's staged quad is (tid&15)*4 for every i -> 8 partials/quad
    pf[tid] = sq4;
    __syncthreads();
    if (tid < 16) {
        float4 s = make_float4(0.f, 0.f, 0.f, 0.f);
#pragma unroll
        for (int j2 = 0; j2 < 8; ++j2) {
            float4 a = pf[tid + 16 * j2];
            s.x += a.x; s.y += a.y; s.z += a.z; s.w += a.w;
        }
        *(float4*)&fbsq_s[tid * 4] = s;
    }
    __syncthreads();
    const float4 q0 = *(const float4*)&fbsq_s[ng * 4];
    float fsq[4] = {q0.x, q0.y, q0.z, q0.w};
#pragma unroll
    for (int kk = 0; kk < 4; ++kk) {
        float bv = 1e30f; int bn = 1 << 28;
#pragma unroll
        for (int j = 0; j < 4; ++j) {          // n ascending within thread
            float sc = fsq[j] - 2.f * acc[kk][j];
            int n = ng * 4 + j;
            if (sc < bv) { bv = sc; bn = n; }
        }
        for (int m = 1; m < 16; m <<= 1) {     // reduce across the 16 ng lanes
            float ov = __shfl_xor(bv, m);
            int   on = __shfl_xor(bn, m);
            if (ov < bv || (ov == bv && on < bn)) { bv = ov; bn = on; }
        }
        if (ng == 0) {
            int k = ks * 32 + kg * 4 + kk;
            candV[(b * K_ + k) * NBLK + blockIdx.x] = bv;
            candN[(b * K_ + k) * NBLK + blockIdx.x] = nb + bn;
        }
    }
}

// ---------------- kernel 5: cross-block argmin + offsets ----------------
// grid (64, 8), block 64. NBLK=144 candidates per (b,k).
__global__ void k_reduce(const float* __restrict__ candV, const int* __restrict__ candN,
                         const int* __restrict__ rowA, const int* __restrict__ colA,
                         int* __restrict__ offR, int* __restrict__ offC) {
    int k = blockIdx.x, b = blockIdx.y, lane = threadIdx.x;
    int base = (b * K_ + k) * NBLK;
    float bv = candV[base + lane]; int bn = candN[base + lane];
    {
        float ov = candV[base + 64 + lane]; int on = candN[base + 64 + lane];
        if (ov < bv || (ov == bv && on < bn)) { bv = ov; bn = on; }
    }
    if (lane < NBLK - 128) {
        float ov = candV[base + 128 + lane]; int on = candN[base + 128 + lane];
        if (ov < bv || (ov == bv && on < bn)) { bv = ov; bn = on; }
    }
    for (int m = 1; m < 64; m <<= 1) {
        float ov = __shfl_xor(bv, m);
        int   on = __shfl_xor(bn, m);
        if (ov < bv || (ov == bv && on < bn)) { bv = ov; bn = on; }
    }
    if (lane == 0) {
        int rB = bn / W_, cB = bn - rB * W_;
        offR[b * K_ + k] = rowA[b * K_ + k] - rB;   // -(rowB - rowA)
        offC[b * K_ + k] = colA[b * K_ + k] - cB;
    }
}

// ---------------- kernel 6: per-batch mode (first-index tie-break) ----------------
__global__ void k_mode(const int* __restrict__ offR, const int* __restrict__ offC,
                       int* __restrict__ out) {
    __shared__ int r_s[64], c_s[64];
    int b = blockIdx.x, k = threadIdx.x;
    r_s[k] = offR[b * 64 + k]; c_s[k] = offC[b * 64 + k];
    __syncthreads();
    int mr = r_s[k], mc = c_s[k], cnt = 0;
#pragma unroll
    for (int j = 0; j < 64; ++j) cnt += (r_s[j] == mr && c_s[j] == mc) ? 1 : 0;
    int bk = k, bc = cnt;
    for (int m = 1; m < 64; m <<= 1) {
        int oc = __shfl_xor(bc, m);
        int ok = __shfl_xor(bk, m);
        if (oc > bc || (oc == bc && ok < bk)) { bc = oc; bk = ok; }
    }
    if (k == 0) { out[b * 2] = r_s[bk]; out[b * 2 + 1] = c_s[bk]; }
}

extern "C" void kernel_launch(void* const* d_in, const int* in_sizes, int n_in,
                              void* d_out, int out_size, void* d_ws, size_t ws_size,
                              hipStream_t stream) {
    const float* A  = (const float*)d_in[0];
    const float* FB = (const float*)d_in[1];
    char* ws = (char*)d_ws;
    float* part  = (float*)(ws + OFF_PARTIAL);
    float* desc  = (float*)(ws + OFF_DESC);
    int*   rowA  = (int*)(ws + OFF_ROWA);
    int*   colA  = (int*)(ws + OFF_COLA);
    int*   flatA = (int*)(ws + OFF_FLATA);
    float* candV = (float*)(ws + OFF_CANDV);
    int*   candN = (int*)(ws + OFF_CANDN);
    int*   offR  = (int*)(ws + OFF_OFFR);
    int*   offC  = (int*)(ws + OFF_OFFC);
    int*   out   = (int*)d_out;

    k_partial<<<dim3((B_ * HW) / 1024, 8), 256, 0, stream>>>(A, part);
    k_select<<<dim3(K_, B_), 64, 0, stream>>>(part, rowA, colA, flatA);
    k_gather<<<dim3((B_ * C_ * K_) / 256), 256, 0, stream>>>(A, flatA, desc);
    k_main<<<dim3(NBLK, 2, B_), 128, 0, stream>>>(FB, desc, candV, candN);
    k_reduce<<<dim3(K_, B_), 64, 0, stream>>>(candV, candN, rowA, colA, offR, offC);
    k_mode<<<dim3(B_), 64, 0, stream>>>(offR, offC, out);
}